// Round 10
// baseline (4247.883 us; speedup 1.0000x reference)
//
#include <hip/hip_runtime.h>

typedef unsigned short u16;
typedef unsigned int u32;
typedef unsigned long long u64;
typedef __attribute__((ext_vector_type(8))) short bf16x8;   // 8 bf16 (4 VGPRs)
typedef __attribute__((ext_vector_type(4))) float f32x4;

#define T_STEPS 1024
#define E_SZ 128
#define U_SZ 256

#define NG 16    // batch groups (16 batches each)
#define MB 16    // batch rows per group
#define NSL 8    // slices per layer (8 L0-wgs + 8 L1-wgs per group)
#define RD 8     // h0 ring depth
#define HS 264   // epilogue LDS row stride (u16)
#define EPAD 136 // padded LDS row stride for x, K=128
#define BSTRIDE 192  // u64 per slice-block: 16 batches x 12 tagged u64

#define POLL_BAIL 60000   // latched fast-fail: broken protocol -> quick wrong answer

// ---- LDS layout (role-dependent), bytes ----
// Weights/stg in MFMA-fragment order (R9: conflict-free b128, verified 10x
// SQ_LDS_BANK_CONFLICT drop).
#define L0_W0T 0
#define L0_R0T 32768
#define L0_X   98304
#define L0_STG 102656
#define L0_G   110848
#define L0_B   119616
#define L1_W1T 0
#define L1_R1T 65536
#define L1_SG0 131072
#define L1_SG1 139264
#define L1_G   147456
#define L1_B   156224
#define SMEM_TOTAL 156800

// ---- exchange state: self-verifying tagged u64 = {3x bf16 | tag16} ----
// Wire format + protocol UNCHANGED since R2 (proven). R7: wave-split staged
// gather. R10: L1 phase reorder (h1 first, h0 refresh under R1-MFMA),
// L0 issue-early, own-slice LDS short-circuit.
__device__ u64 g_exH0[RD * NG * NSL * BSTRIDE];  // 1.5 MiB h0 ring
__device__ u64 g_exH1[2 * NG * NSL * BSTRIDE];   // h1 parity ring
__device__ int g_pr[NG * NSL * 16];              // L1 consume progress (ring guard)
__device__ u32 g_run;                            // run/generation counter
__device__ int g_isF32;

__device__ __forceinline__ float bf2f(u16 u) {
  union { u32 i; float f; } v; v.i = ((u32)u) << 16; return v.f;
}
__device__ __forceinline__ u16 f2bf(float f) {
  union { u32 i; float f; } v; v.f = f;
  u32 r = v.i + 0x7fffu + ((v.i >> 16) & 1u);
  return (u16)(r >> 16);
}
__device__ __forceinline__ float sig_(float x) { return 1.f / (1.f + __expf(-x)); }
__device__ __forceinline__ float tnh_(float x) { return 2.f / (1.f + __expf(-2.f * x)) - 1.f; }

// ---- dtype probe: bumps run counter, zeroes ring guard ----
extern "C" __global__ void dtype_probe(const void* W0v) {
  __shared__ int cntBig;
  if (threadIdx.x == 0) cntBig = 0;
  __syncthreads();
  const u16* u = (const u16*)W0v;
  int big = 0;
  for (int i = threadIdx.x; i < 4096; i += 256)
    if ((u[i] & 0x7F80u) >= 0x4100u) big++;
  atomicAdd(&cntBig, big);
  __syncthreads();
  for (int i = threadIdx.x; i < NG * NSL * 16; i += 256) g_pr[i] = 0;
  if (threadIdx.x == 0) {
    g_isF32 = (cntBig > 100) ? 1 : 0;
    g_run = g_run + 1;               // fresh tag generation each launch
  }
}

__device__ __forceinline__ u64 ldAtom(const u64* p) {
  return __hip_atomic_load(p, __ATOMIC_RELAXED, __HIP_MEMORY_SCOPE_AGENT);
}

// ---- ring-guard poll returning min observed progress (amortizes re-polls) ----
__device__ __forceinline__ int wavePollMin(const int* fA, int tgt, int lane,
                                           int& dead) {
  if (dead) return tgt;
  const int* p = (lane < 8) ? fA + lane * 16 : nullptr;
  int ok = (p == nullptr);
  int v = 0x7fffffff;
  int it = 0;
  while (!__all(ok)) {
    if (!ok) {
      v = __hip_atomic_load(p, __ATOMIC_RELAXED, __HIP_MEMORY_SCOPE_AGENT);
      ok = v >= tgt;
    }
    if (++it > POLL_BAIL) { dead = 1; break; }
    if (it > 48) __builtin_amdgcn_s_sleep(1);
  }
  __atomic_signal_fence(__ATOMIC_ACQUIRE);
  int m = (lane < 8) ? v : 0x7fffffff;
#pragma unroll
  for (int off = 4; off; off >>= 1) {
    int o = __shfl_down(m, off);
    m = m < o ? m : o;
  }
  return __shfl(m, 0);
}

__device__ __forceinline__ u32 tagBad(u64 a, u64 b, u64 c, u32 etag) {
  return (((u32)(a >> 48)) ^ etag) | (((u32)(b >> 48)) ^ etag) |
         (((u32)(c >> 48)) ^ etag);
}

// ---- unpack 3 tagged u64 -> 16B fragment, write to LDS staging.
// Fragment order: slot = slice*64 + quad*16 + ml (conflict-free, R9). ----
__device__ __forceinline__ void unpackToLds(const u64 q0, const u64 q1, const u64 q2,
                                            u16* __restrict__ stg, int slice,
                                            int ml, int quad) {
  u32 a0 = (u32)q0, a1 = (u32)(q0 >> 32);
  u32 b0 = (u32)q1, b1 = (u32)(q1 >> 32);
  u32 c0 = (u32)q2;
  uint4 F;
  F.x = a0;
  F.y = (a1 & 0xFFFFu) | (b0 << 16);
  F.z = (b0 >> 16) | (b1 << 16);
  F.w = c0;
  *(uint4*)(stg + (((slice << 6) + (quad << 4) + ml) << 3)) = F;
}

// ---- blocking poll on a pair of slices (skip = own slot, -1 = none) ----
__device__ __forceinline__ void pollPair(const u64* __restrict__ pA,
                                         const u64* __restrict__ pB,
                                         u32 etag, int skip,
                                         u64& a0, u64& a1, u64& a2,
                                         u64& b0, u64& b1, u64& b2, int& dead) {
  int it = 0;
  while (true) {
    u32 badA = (skip == 0) ? 0u : tagBad(a0, a1, a2, etag);
    u32 badB = (skip == 1) ? 0u : tagBad(b0, b1, b2, etag);
    if (!__any((badA | badB) != 0)) break;
    if (dead) break;
    if (++it > POLL_BAIL) { dead = 1; break; }
    if (badA) { a0 = ldAtom(pA); a1 = ldAtom(pA + 1); a2 = ldAtom(pA + 2); }
    if (badB) { b0 = ldAtom(pB); b1 = ldAtom(pB + 1); b2 = ldAtom(pB + 2); }
    if (it > 8) __builtin_amdgcn_s_sleep(1);
  }
  __atomic_signal_fence(__ATOMIC_ACQUIRE);
}

extern "C" __global__ void __launch_bounds__(256, 1)
lstm_fused(const int* __restrict__ tokens, const void* __restrict__ emb,
           const void* __restrict__ W0, const void* __restrict__ R0, const void* __restrict__ b0,
           const void* __restrict__ W1, const void* __restrict__ R1, const void* __restrict__ b1,
           const void* __restrict__ Wout, const void* __restrict__ bout,
           void* __restrict__ outv) {
  extern __shared__ char smem[];

  const int tid = threadIdx.x;
  const int b = blockIdx.x;
  const int g = b & (NG - 1);
  const int w = b >> 4;
  const int role = w >> 3;             // 0 = layer-0 wg, 1 = layer-1 wg
  const int sl = w & 7;
  const int isF32 = g_isF32;
  const u32 tagB = ((u32)g_run) << 10;

  auto ldf = [&](const void* p, int idx) -> float {
    return isF32 ? ((const float*)p)[idx] : bf2f(((const u16*)p)[idx]);
  };

  const int lane = tid & 63;
  const int wv = tid >> 6;            // wave = gate q (output tiles 2wv, 2wv+1)
  const int ml = lane & 15;
  const int quad = lane >> 4;
  const int um = tid >> 4;
  const int un = tid & 15;
  const int lfr = (quad << 4) + ml;   // fragment lane slot (== lane)
  // own-slice slot within this wave's staged pair ({2wv, 2wv+1}); -1 if none
  const int slotOwn = ((sl >> 1) == wv) ? (sl & 1) : -1;

  // cell/post thread mapping: (batch mB, slot uS) ; slot uS<12 holds 3 (or 2)
  // consecutive units: q=uS/3, s=uS%3, kb=8q+3s (s<2: 3 units; s==2: 2 units)
  const int mB = tid >> 4;
  const int uS = tid & 15;
  const int qS = uS / 3;
  const int sS = uS - qS * 3;
  const int kb = (qS << 3) + 3 * sS;
  const int nFull = (sS != 2);

  int* flp = g_pr + (g << 3) * 16;
  int dead = 0;

  if (role == 0) {
    // ================= LAYER-0 WORKGROUP =================
    u16* w0t = (u16*)(smem + L0_W0T);
    u16* r0t = (u16*)(smem + L0_R0T);
    u16* ldsX = (u16*)(smem + L0_X);
    u16* stg = (u16*)(smem + L0_STG);
    float* ldsG = (float*)(smem + L0_G);
    float* ldsB = (float*)(smem + L0_B);

    // weights -> fragment-order LDS (conflict-free b128 reads)
    for (int i = tid; i < 128 * 128; i += 256) {
      int k = i >> 7, n = i & 127;
      int col = ((n >> 5) << 8) + (sl << 5) + (n & 31);
      int wv_ = n >> 5, s_ = (n >> 4) & 1, ml_ = n & 15;
      int j_ = k >> 5, q_ = (k >> 3) & 3, e_ = k & 7;
      int dst = ((((wv_ << 1) + s_) * 4 + j_) * 64 + (q_ << 4) + ml_) * 8 + e_;
      w0t[dst] = f2bf(ldf(W0, k * 1024 + col));
    }
    for (int i = tid; i < 128 * 256; i += 256) {
      int k = i >> 7, n = i & 127;
      int col = ((n >> 5) << 8) + (sl << 5) + (n & 31);
      int wv_ = n >> 5, s_ = (n >> 4) & 1, ml_ = n & 15;
      int j_ = k >> 5, q_ = (k >> 3) & 3, e_ = k & 7;
      int dst = ((((wv_ << 1) + s_) * 8 + j_) * 64 + (q_ << 4) + ml_) * 8 + e_;
      r0t[dst] = f2bf(ldf(R0, k * 1024 + col));
    }
    if (tid < 128) {
      int col = ((tid >> 5) << 8) + (sl << 5) + (tid & 31);
      ldsB[tid] = ldf(b0, col);
    }

    float cst[3] = {0.f, 0.f, 0.f};
    const int tokBase = (g * MB + um) * T_STEPS;
    int prMin = 0;                    // cached min L1 progress (ring guard)

    float4 xfA, xfB; uint4 xbf;
    {
      int tok = tokens[tokBase];
      if (isF32) {
        const float* row = (const float*)emb + (u64)tok * E_SZ + (un << 3);
        xfA = *(const float4*)row; xfB = *(const float4*)(row + 4);
      } else {
        xbf = *(const uint4*)((const u16*)emb + (u64)tok * E_SZ + (un << 3));
      }
    }
    __syncthreads();

    const int row0 = (wv << 5) + ml;
    const u16* brA0 = w0t + (u32)(((wv << 1) + 0) * 256 + lfr) * 8;  // +kc*512
    const u16* brB0 = w0t + (u32)(((wv << 1) + 1) * 256 + lfr) * 8;
    const u16* brA2 = r0t + (u32)(((wv << 1) + 0) * 512 + lfr) * 8;  // +j*512
    const u16* brB2 = r0t + (u32)(((wv << 1) + 1) * 512 + lfr) * 8;

    for (int t = 0; t < T_STEPS; t++) {
      // ring guard at top: off the post critical path
      if (t >= RD && prMin < t - RD + 1)
        prMin = wavePollMin(flp, t - RD + 1, lane, dead);

      // commit x_t
      {
        uint4 pk;
        if (isF32) {
          pk.x = (u32)f2bf(xfA.x) | ((u32)f2bf(xfA.y) << 16);
          pk.y = (u32)f2bf(xfA.z) | ((u32)f2bf(xfA.w) << 16);
          pk.z = (u32)f2bf(xfB.x) | ((u32)f2bf(xfB.y) << 16);
          pk.w = (u32)f2bf(xfB.z) | ((u32)f2bf(xfB.w) << 16);
        } else pk = xbf;
        *(uint4*)(ldsX + um * EPAD + (un << 3)) = pk;
      }
      __syncthreads();   // B1: x visible

      // ISSUE h0_{t-1} gather early (skip own slot): first RT overlaps W0
      u64 qa0 = 0, qa1 = 0, qa2 = 0, qb0 = 0, qb1 = 0, qb2 = 0;
      const u64* gp0 = nullptr; const u64* gp1 = nullptr;
      if (t > 0) {
        const u64* base = g_exH0 +
            (u64)((((t - 1) & (RD - 1)) * NG + g) * NSL) * BSTRIDE;
        gp0 = base + (u64)(wv << 1) * BSTRIDE + ml * 12 + quad * 3;
        gp1 = gp0 + BSTRIDE;
        if (slotOwn != 0) { qa0 = ldAtom(gp0); qa1 = ldAtom(gp0 + 1); qa2 = ldAtom(gp0 + 2); }
        if (slotOwn != 1) { qb0 = ldAtom(gp1); qb1 = ldAtom(gp1 + 1); qb2 = ldAtom(gp1 + 2); }
      }

      float ba = ldsB[row0], bb = ldsB[row0 + 16];
      f32x4 acA = {ba, ba, ba, ba}, acB = {bb, bb, bb, bb};

      // x_t @ W0 (no dependence on h0; gather loads in flight)
      {
        const u16* ar = ldsX + ml * EPAD + (quad << 3);
#pragma unroll
        for (int kc = 0; kc < 4; kc++) {
          bf16x8 av = *(const bf16x8*)(ar + kc * 32);
          acA = __builtin_amdgcn_mfma_f32_16x16x32_bf16(av, *(const bf16x8*)(brA0 + (kc << 9)), acA, 0, 0, 0);
          acB = __builtin_amdgcn_mfma_f32_16x16x32_bf16(av, *(const bf16x8*)(brB0 + (kc << 9)), acB, 0, 0, 0);
        }
      }

      // COMPLETE gather: poll + unpack non-own (own written by cell(t-1))
      if (t > 0) {
        pollPair(gp0, gp1, (tagB + t) & 0xFFFFu, slotOwn,
                 qa0, qa1, qa2, qb0, qb1, qb2, dead);
        if (slotOwn != 0) unpackToLds(qa0, qa1, qa2, stg, (wv << 1), ml, quad);
        if (slotOwn != 1) unpackToLds(qb0, qb1, qb2, stg, (wv << 1) + 1, ml, quad);
      }
      __syncthreads();   // B2: stg visible to all waves

      if (t > 0) {
#pragma unroll
        for (int j = 0; j < NSL; j++) {
          bf16x8 fv = *(const bf16x8*)(stg + (((j << 6) + lfr) << 3));
          acA = __builtin_amdgcn_mfma_f32_16x16x32_bf16(fv, *(const bf16x8*)(brA2 + (j << 9)), acA, 0, 0, 0);
          acB = __builtin_amdgcn_mfma_f32_16x16x32_bf16(fv, *(const bf16x8*)(brB2 + (j << 9)), acB, 0, 0, 0);
        }
      }

      // gates
#pragma unroll
      for (int r = 0; r < 4; r++) {
        int m = (quad << 2) + r;
        float gA = (wv == 2) ? tnh_(acA[r]) : sig_(acA[r]);
        float gB = (wv == 2) ? tnh_(acB[r]) : sig_(acB[r]);
        ldsG[row0 * 17 + m] = gA;
        ldsG[(row0 + 16) * 17 + m] = gB;
      }
      __syncthreads();   // B3

      // cell update -> post + own-slice direct staging for next gather
      if (uS < 12) {
        u64 val = ((u64)((tagB + t + 1) & 0xFFFFu)) << 48;
        u16 hw0 = 0, hw1 = 0, hw2 = 0;
#pragma unroll
        for (int i2 = 0; i2 < 3; i2++) {
          if (i2 < 2 || nFull) {
            int k = kb + i2;
            float iv = ldsG[k * 17 + mB];
            float fv = ldsG[(32 + k) * 17 + mB];
            float gv = ldsG[(64 + k) * 17 + mB];
            float ov = ldsG[(96 + k) * 17 + mB];
            float c = fv * cst[i2] + iv * gv; cst[i2] = c;
            u16 hh = f2bf(ov * tnh_(c));
            if (i2 == 0) hw0 = hh; else if (i2 == 1) hw1 = hh; else hw2 = hh;
            val |= ((u64)hh) << (16 * i2);
          }
        }
        // own-slice fragment write (read by all waves after B2(t+1))
        u16* own = stg + (((sl << 6) + (qS << 4) + mB) << 3) + 3 * sS;
        own[0] = hw0; own[1] = hw1;
        if (nFull) own[2] = hw2;
        u64 elem = (u64)(((t & (RD - 1)) * NG + g) * NSL + sl) * BSTRIDE +
                   mB * 12 + uS;
        __hip_atomic_store(g_exH0 + elem, val,
                           __ATOMIC_RELAXED, __HIP_MEMORY_SCOPE_AGENT);
      }

      // x_{t+1} prefetch in flight across next rendezvous
      if (t + 1 < T_STEPS) {
        int tok = tokens[tokBase + t + 1];
        if (isF32) {
          const float* row = (const float*)emb + (u64)tok * E_SZ + (un << 3);
          xfA = *(const float4*)row; xfB = *(const float4*)(row + 4);
        } else {
          xbf = *(const uint4*)((const u16*)emb + (u64)tok * E_SZ + (un << 3));
        }
      }
    }
  } else {
    // ================= LAYER-1 WORKGROUP =================
    u16* w1t = (u16*)(smem + L1_W1T);
    u16* r1t = (u16*)(smem + L1_R1T);
    u16* stg0 = (u16*)(smem + L1_SG0);
    u16* stg1 = (u16*)(smem + L1_SG1);
    float* ldsG = (float*)(smem + L1_G);
    float* ldsB = (float*)(smem + L1_B);

    for (int i = tid; i < 128 * 256; i += 256) {
      int k = i >> 7, n = i & 127;
      int col = ((n >> 5) << 8) + (sl << 5) + (n & 31);
      int wv_ = n >> 5, s_ = (n >> 4) & 1, ml_ = n & 15;
      int j_ = k >> 5, q_ = (k >> 3) & 3, e_ = k & 7;
      int dst = ((((wv_ << 1) + s_) * 8 + j_) * 64 + (q_ << 4) + ml_) * 8 + e_;
      w1t[dst] = f2bf(ldf(W1, k * 1024 + col));
      r1t[dst] = f2bf(ldf(R1, k * 1024 + col));
    }
    if (tid < 128) {
      int col = ((tid >> 5) << 8) + (sl << 5) + (tid & 31);
      ldsB[tid] = ldf(b1, col);
    }
    __syncthreads();

    float cst[3] = {0.f, 0.f, 0.f};
    const int row0 = (wv << 5) + ml;
    const u16* brA1 = w1t + (u32)(((wv << 1) + 0) * 512 + lfr) * 8;
    const u16* brB1 = w1t + (u32)(((wv << 1) + 1) * 512 + lfr) * 8;
    const u16* brA2 = r1t + (u32)(((wv << 1) + 0) * 512 + lfr) * 8;
    const u16* brB2 = r1t + (u32)(((wv << 1) + 1) * 512 + lfr) * 8;

    for (int t = 0; t < T_STEPS; t++) {
      const u32 e1 = (tagB + t) & 0xFFFFu;        // h1_{t-1} tag
      const u32 e0 = (tagB + t + 1) & 0xFFFFu;    // h0_t tag
      const int off = ml * 12 + quad * 3;
      const u64* h1b = g_exH1 +
          (u64)((((t - 1) & 1) * NG + g) * NSL) * BSTRIDE;
      const u64* h0b = g_exH0 +
          (u64)(((t & (RD - 1)) * NG + g) * NSL) * BSTRIDE;
      const u64* p1a = h1b + (u64)(wv << 1) * BSTRIDE + off;
      const u64* p1b = p1a + BSTRIDE;
      const u64* p0a = h0b + (u64)(wv << 1) * BSTRIDE + off;
      const u64* p0b = p0a + BSTRIDE;

      // ISSUE h1 first (completed first), then h0 (completed after R1-MFMA)
      u64 ya0 = 0, ya1 = 0, ya2 = 0, yb0 = 0, yb1 = 0, yb2 = 0;
      if (t > 0) {
        if (slotOwn != 0) { ya0 = ldAtom(p1a); ya1 = ldAtom(p1a + 1); ya2 = ldAtom(p1a + 2); }
        if (slotOwn != 1) { yb0 = ldAtom(p1b); yb1 = ldAtom(p1b + 1); yb2 = ldAtom(p1b + 2); }
      }
      u64 xa0 = ldAtom(p0a), xa1 = ldAtom(p0a + 1), xa2 = ldAtom(p0a + 2);
      u64 xb0 = ldAtom(p0b), xb1 = ldAtom(p0b + 1), xb2 = ldAtom(p0b + 2);

      // COMPLETE h1 (pacing self-loop; own slice short-circuited via LDS)
      if (t > 0) {
        pollPair(p1a, p1b, e1, slotOwn, ya0, ya1, ya2, yb0, yb1, yb2, dead);
        if (slotOwn != 0) unpackToLds(ya0, ya1, ya2, stg1, (wv << 1), ml, quad);
        if (slotOwn != 1) unpackToLds(yb0, yb1, yb2, stg1, (wv << 1) + 1, ml, quad);
      }
      __syncthreads();   // B1: stg1 visible

      // h0 refresh pass: reload stale entries; reloads fly under R1-MFMA
      if (tagBad(xa0, xa1, xa2, e0)) { xa0 = ldAtom(p0a); xa1 = ldAtom(p0a + 1); xa2 = ldAtom(p0a + 2); }
      if (tagBad(xb0, xb1, xb2, e0)) { xb0 = ldAtom(p0b); xb1 = ldAtom(p0b + 1); xb2 = ldAtom(p0b + 2); }

      float ba = ldsB[row0], bb = ldsB[row0 + 16];
      f32x4 acA = {ba, ba, ba, ba}, acB = {bb, bb, bb, bb};

      // h1_{t-1} @ R1 (h0 reloads in flight)
      if (t > 0) {
#pragma unroll
        for (int j = 0; j < NSL; j++) {
          bf16x8 fv = *(const bf16x8*)(stg1 + (((j << 6) + lfr) << 3));
          acA = __builtin_amdgcn_mfma_f32_16x16x32_bf16(fv, *(const bf16x8*)(brA2 + (j << 9)), acA, 0, 0, 0);
          acB = __builtin_amdgcn_mfma_f32_16x16x32_bf16(fv, *(const bf16x8*)(brB2 + (j << 9)), acB, 0, 0, 0);
        }
      }

      // COMPLETE h0, stage
      pollPair(p0a, p0b, e0, -1, xa0, xa1, xa2, xb0, xb1, xb2, dead);
      unpackToLds(xa0, xa1, xa2, stg0, (wv << 1), ml, quad);
      unpackToLds(xb0, xb1, xb2, stg0, (wv << 1) + 1, ml, quad);
      __syncthreads();   // B2: stg0 visible

      // ring-slot release (all waves' h0 staging done)
      if (tid == 0) {
        __atomic_signal_fence(__ATOMIC_RELEASE);
        __hip_atomic_store(g_pr + ((g << 3) + sl) * 16, t + 1,
                           __ATOMIC_RELAXED, __HIP_MEMORY_SCOPE_AGENT);
      }

      // h0_t @ W1
#pragma unroll
      for (int j = 0; j < NSL; j++) {
        bf16x8 fv = *(const bf16x8*)(stg0 + (((j << 6) + lfr) << 3));
        acA = __builtin_amdgcn_mfma_f32_16x16x32_bf16(fv, *(const bf16x8*)(brA1 + (j << 9)), acA, 0, 0, 0);
        acB = __builtin_amdgcn_mfma_f32_16x16x32_bf16(fv, *(const bf16x8*)(brB1 + (j << 9)), acB, 0, 0, 0);
      }

      // gates
#pragma unroll
      for (int r = 0; r < 4; r++) {
        int m = (quad << 2) + r;
        float gA = (wv == 2) ? tnh_(acA[r]) : sig_(acA[r]);
        float gB = (wv == 2) ? tnh_(acB[r]) : sig_(acB[r]);
        ldsG[row0 * 17 + m] = gA;
        ldsG[(row0 + 16) * 17 + m] = gB;
      }
      __syncthreads();   // B3

      // cell update -> post + own-slice direct staging (for next h1 gather)
      if (uS < 12) {
        u64 val = ((u64)((tagB + t + 1) & 0xFFFFu)) << 48;
        u16 hw0 = 0, hw1 = 0, hw2 = 0;
#pragma unroll
        for (int i2 = 0; i2 < 3; i2++) {
          if (i2 < 2 || nFull) {
            int k = kb + i2;
            float iv = ldsG[k * 17 + mB];
            float fv = ldsG[(32 + k) * 17 + mB];
            float gv = ldsG[(64 + k) * 17 + mB];
            float ov = ldsG[(96 + k) * 17 + mB];
            float c = fv * cst[i2] + iv * gv; cst[i2] = c;
            u16 hh = f2bf(ov * tnh_(c));
            if (i2 == 0) hw0 = hh; else if (i2 == 1) hw1 = hh; else hw2 = hh;
            val |= ((u64)hh) << (16 * i2);
          }
        }
        u16* own = stg1 + (((sl << 6) + (qS << 4) + mB) << 3) + 3 * sS;
        own[0] = hw0; own[1] = hw1;
        if (nFull) own[2] = hw2;
        u64 elem = (u64)(((t & 1) * NG + g) * NSL + sl) * BSTRIDE +
                   mB * 12 + uS;
        __hip_atomic_store(g_exH1 + elem, val,
                           __ATOMIC_RELAXED, __HIP_MEMORY_SCOPE_AGENT);
      }
    }

    // epilogue: logits from h1_{T-1} (staging buffers reused as gather area)
    if (sl == 0) {
      __syncthreads();
      u16* ldsEpi = stg0;   // 8448B needed <= 16384B of SG0+SG1
      const u32 etag = (tagB + T_STEPS) & 0xFFFFu;
      if (uS < 12) {
        for (int sp = 0; sp < 8; sp++) {
          const u64* p = g_exH1 +
              (u64)(((1) * NG + g) * NSL + sp) * BSTRIDE + mB * 12 + uS;
          u64 v; int it = 0;
          while (true) {
            v = ldAtom(p);
            if ((u32)(v >> 48) == etag) break;
            if (dead) break;
            if (++it > POLL_BAIL) { dead = 1; break; }
            if (it > 8) __builtin_amdgcn_s_sleep(1);
          }
          u16* dst = ldsEpi + mB * HS + (sp << 5) + kb;
          dst[0] = (u16)v;
          dst[1] = (u16)(v >> 16);
          if (nFull) dst[2] = (u16)(v >> 32);
        }
      }
      __syncthreads();
      float* woutf = ldsG;
      float* red = ldsG + 272;
      woutf[tid] = ldf(Wout, tid);
      __syncthreads();
      float p = 0.f;
#pragma unroll
      for (int j = 0; j < 16; j++)
        p += bf2f(ldsEpi[um * HS + (un << 4) + j]) * woutf[(un << 4) + j];
      red[um * 17 + un] = p;
      __syncthreads();
      if (tid < 16) {
        float sum = ldf(bout, 0);
#pragma unroll
        for (int j = 0; j < 16; j++) sum += red[tid * 17 + j];
        float val = sig_(sum);
        if (isF32) ((float*)outv)[g * MB + tid] = val;
        else       ((u16*)outv)[g * MB + tid] = f2bf(val);
      }
    }
  }
}

extern "C" void kernel_launch(void* const* d_in, const int* in_sizes, int n_in,
                              void* d_out, int out_size, void* d_ws, size_t ws_size,
                              hipStream_t stream) {
  const int* tokens = (const int*)d_in[0];
  const void* emb  = d_in[1];
  const void* W0   = d_in[2];
  const void* R0   = d_in[3];
  const void* b0   = d_in[4];
  const void* W1   = d_in[5];
  const void* R1   = d_in[6];
  const void* b1   = d_in[7];
  const void* Wout = d_in[8];
  const void* bout = d_in[9];

  hipFuncSetAttribute((const void*)lstm_fused,
                      hipFuncAttributeMaxDynamicSharedMemorySize, SMEM_TOTAL);

  dtype_probe<<<dim3(1), dim3(256), 0, stream>>>(W0);

  // 256 wgs (16 groups x (8 L0 + 8 L1)), 1 wg/CU: co-resident.
  lstm_fused<<<dim3(256), dim3(256), SMEM_TOTAL, stream>>>(
      tokens, emb, W0, R0, b0, W1, R1, b1, Wout, bout, d_out);
}

// Round 11
// 3308.549 us; speedup vs baseline: 1.2839x; 1.2839x over previous
//
#include <hip/hip_runtime.h>

typedef unsigned short u16;
typedef unsigned int u32;
typedef unsigned long long u64;
typedef __attribute__((ext_vector_type(8))) short bf16x8;   // 8 bf16 (4 VGPRs)
typedef __attribute__((ext_vector_type(4))) float f32x4;

#define T_STEPS 1024
#define E_SZ 128
#define U_SZ 256

#define NG 16    // batch groups (16 batches each)
#define MB 16    // batch rows per group
#define NSL 8    // slices per layer (8 L0-wgs + 8 L1-wgs per group)
#define RD 8     // h0 ring depth
#define HS 264   // epilogue LDS row stride (u16)
#define EPAD 136 // padded LDS row stride for x, K=128
#define BSTRIDE 192  // u64 per slice-block: 16 batches x 12 tagged u64

#define POLL_BAIL 60000   // latched fast-fail: broken protocol -> quick wrong answer

// ---- LDS layout (role-dependent), bytes ----
// Weights/stg in MFMA-fragment order (R9: conflict-free b128, verified 10x
// SQ_LDS_BANK_CONFLICT drop).
#define L0_W0T 0
#define L0_R0T 32768
#define L0_X   98304
#define L0_STG 102656
#define L0_G   110848
#define L0_B   119616
#define L1_W1T 0
#define L1_R1T 65536
#define L1_SG0 131072
#define L1_SG1 139264
#define L1_G   147456
#define L1_B   156224
#define SMEM_TOTAL 156800

// ---- exchange state: self-verifying tagged u64 = {3x bf16 | tag16} ----
// Wire format + protocol UNCHANGED since R2 (proven). R7: wave-split staged
// gather. R11: own-slice LDS short-circuit (skip polling own slice) + L1
// phase split with CORRECT orientation (W1 compute inside the h1 wait
// window; h1 is the pacer, h0 is ring-ahead). NO early issues (R6/R10).
__device__ u64 g_exH0[RD * NG * NSL * BSTRIDE];  // 1.5 MiB h0 ring
__device__ u64 g_exH1[2 * NG * NSL * BSTRIDE];   // h1 parity ring
__device__ int g_pr[NG * NSL * 16];              // L1 consume progress (ring guard)
__device__ u32 g_run;                            // run/generation counter
__device__ int g_isF32;

__device__ __forceinline__ float bf2f(u16 u) {
  union { u32 i; float f; } v; v.i = ((u32)u) << 16; return v.f;
}
__device__ __forceinline__ u16 f2bf(float f) {
  union { u32 i; float f; } v; v.f = f;
  u32 r = v.i + 0x7fffu + ((v.i >> 16) & 1u);
  return (u16)(r >> 16);
}
__device__ __forceinline__ float sig_(float x) { return 1.f / (1.f + __expf(-x)); }
__device__ __forceinline__ float tnh_(float x) { return 2.f / (1.f + __expf(-2.f * x)) - 1.f; }

// ---- dtype probe: bumps run counter, zeroes ring guard ----
extern "C" __global__ void dtype_probe(const void* W0v) {
  __shared__ int cntBig;
  if (threadIdx.x == 0) cntBig = 0;
  __syncthreads();
  const u16* u = (const u16*)W0v;
  int big = 0;
  for (int i = threadIdx.x; i < 4096; i += 256)
    if ((u[i] & 0x7F80u) >= 0x4100u) big++;
  atomicAdd(&cntBig, big);
  __syncthreads();
  for (int i = threadIdx.x; i < NG * NSL * 16; i += 256) g_pr[i] = 0;
  if (threadIdx.x == 0) {
    g_isF32 = (cntBig > 100) ? 1 : 0;
    g_run = g_run + 1;               // fresh tag generation each launch
  }
}

__device__ __forceinline__ u64 ldAtom(const u64* p) {
  return __hip_atomic_load(p, __ATOMIC_RELAXED, __HIP_MEMORY_SCOPE_AGENT);
}

// ---- ring-guard poll returning min observed progress (amortizes re-polls) ----
__device__ __forceinline__ int wavePollMin(const int* fA, int tgt, int lane,
                                           int& dead) {
  if (dead) return tgt;
  const int* p = (lane < 8) ? fA + lane * 16 : nullptr;
  int ok = (p == nullptr);
  int v = 0x7fffffff;
  int it = 0;
  while (!__all(ok)) {
    if (!ok) {
      v = __hip_atomic_load(p, __ATOMIC_RELAXED, __HIP_MEMORY_SCOPE_AGENT);
      ok = v >= tgt;
    }
    if (++it > POLL_BAIL) { dead = 1; break; }
    if (it > 48) __builtin_amdgcn_s_sleep(1);
  }
  __atomic_signal_fence(__ATOMIC_ACQUIRE);
  int m = (lane < 8) ? v : 0x7fffffff;
#pragma unroll
  for (int off = 4; off; off >>= 1) {
    int o = __shfl_down(m, off);
    m = m < o ? m : o;
  }
  return __shfl(m, 0);
}

__device__ __forceinline__ u32 tagBad(u64 a, u64 b, u64 c, u32 etag) {
  return (((u32)(a >> 48)) ^ etag) | (((u32)(b >> 48)) ^ etag) |
         (((u32)(c >> 48)) ^ etag);
}

// ---- unpack 3 tagged u64 -> 16B fragment, write to LDS staging.
// Fragment order: slot = slice*64 + quad*16 + ml (conflict-free, R9). ----
__device__ __forceinline__ void unpackToLds(const u64 q0, const u64 q1, const u64 q2,
                                            u16* __restrict__ stg, int slice,
                                            int ml, int quad) {
  u32 a0 = (u32)q0, a1 = (u32)(q0 >> 32);
  u32 b0 = (u32)q1, b1 = (u32)(q1 >> 32);
  u32 c0 = (u32)q2;
  uint4 F;
  F.x = a0;
  F.y = (a1 & 0xFFFFu) | (b0 << 16);
  F.z = (b0 >> 16) | (b1 << 16);
  F.w = c0;
  *(uint4*)(stg + (((slice << 6) + (quad << 4) + ml) << 3)) = F;
}

// ---- wave-split staged gather, ONE ring: wave wv polls+stages slices
// {2wv, 2wv+1}; lane (ml,quad) owns 3 u64 per slice. skip = own slot
// (written directly to LDS by cell(t-1); never polled), -1 = none. ----
__device__ __forceinline__ void stageOne(const u64* __restrict__ base, u32 etag,
                                         u16* __restrict__ stg,
                                         int wv, int ml, int quad, int skip,
                                         int& dead) {
  const int j0 = wv << 1;
  const u64* p0 = base + (u64)j0 * BSTRIDE + ml * 12 + quad * 3;
  const u64* p1 = p0 + BSTRIDE;
  u64 qa0 = 0, qa1 = 0, qa2 = 0, qb0 = 0, qb1 = 0, qb2 = 0;
  if (skip != 0) { qa0 = ldAtom(p0); qa1 = ldAtom(p0 + 1); qa2 = ldAtom(p0 + 2); }
  if (skip != 1) { qb0 = ldAtom(p1); qb1 = ldAtom(p1 + 1); qb2 = ldAtom(p1 + 2); }
  int it = 0;
  while (true) {
    u32 badA = (skip == 0) ? 0u : tagBad(qa0, qa1, qa2, etag);
    u32 badB = (skip == 1) ? 0u : tagBad(qb0, qb1, qb2, etag);
    if (!__any((badA | badB) != 0)) break;
    if (dead) break;
    if (++it > POLL_BAIL) { dead = 1; break; }
    if (badA) { qa0 = ldAtom(p0); qa1 = ldAtom(p0 + 1); qa2 = ldAtom(p0 + 2); }
    if (badB) { qb0 = ldAtom(p1); qb1 = ldAtom(p1 + 1); qb2 = ldAtom(p1 + 2); }
    if (it > 8) __builtin_amdgcn_s_sleep(1);
  }
  __atomic_signal_fence(__ATOMIC_ACQUIRE);
  if (skip != 0) unpackToLds(qa0, qa1, qa2, stg, j0, ml, quad);
  if (skip != 1) unpackToLds(qb0, qb1, qb2, stg, j0 + 1, ml, quad);
}

extern "C" __global__ void __launch_bounds__(256, 1)
lstm_fused(const int* __restrict__ tokens, const void* __restrict__ emb,
           const void* __restrict__ W0, const void* __restrict__ R0, const void* __restrict__ b0,
           const void* __restrict__ W1, const void* __restrict__ R1, const void* __restrict__ b1,
           const void* __restrict__ Wout, const void* __restrict__ bout,
           void* __restrict__ outv) {
  extern __shared__ char smem[];

  const int tid = threadIdx.x;
  const int b = blockIdx.x;
  const int g = b & (NG - 1);
  const int w = b >> 4;
  const int role = w >> 3;             // 0 = layer-0 wg, 1 = layer-1 wg
  const int sl = w & 7;
  const int isF32 = g_isF32;
  const u32 tagB = ((u32)g_run) << 10;

  auto ldf = [&](const void* p, int idx) -> float {
    return isF32 ? ((const float*)p)[idx] : bf2f(((const u16*)p)[idx]);
  };

  const int lane = tid & 63;
  const int wv = tid >> 6;            // wave = gate q (output tiles 2wv, 2wv+1)
  const int ml = lane & 15;
  const int quad = lane >> 4;
  const int um = tid >> 4;
  const int un = tid & 15;
  const int lfr = (quad << 4) + ml;   // fragment lane slot (== lane)
  // own-slice slot within this wave's staged pair ({2wv, 2wv+1}); -1 if none.
  // Applies only to the ring this wg POSTS to (L0: h0, L1: h1).
  const int skipMy = ((sl >> 1) == wv) ? (sl & 1) : -1;

  // cell/post thread mapping: (batch mB, slot uS) ; slot uS<12 holds 3 (or 2)
  // consecutive units: q=uS/3, s=uS%3, kb=8q+3s (s<2: 3 units; s==2: 2 units)
  const int mB = tid >> 4;
  const int uS = tid & 15;
  const int qS = uS / 3;
  const int sS = uS - qS * 3;
  const int kb = (qS << 3) + 3 * sS;
  const int nFull = (sS != 2);

  int* flp = g_pr + (g << 3) * 16;
  int dead = 0;

  if (role == 0) {
    // ================= LAYER-0 WORKGROUP =================
    u16* w0t = (u16*)(smem + L0_W0T);
    u16* r0t = (u16*)(smem + L0_R0T);
    u16* ldsX = (u16*)(smem + L0_X);
    u16* stg = (u16*)(smem + L0_STG);
    float* ldsG = (float*)(smem + L0_G);
    float* ldsB = (float*)(smem + L0_B);

    // weights -> fragment-order LDS (conflict-free b128 reads)
    for (int i = tid; i < 128 * 128; i += 256) {
      int k = i >> 7, n = i & 127;
      int col = ((n >> 5) << 8) + (sl << 5) + (n & 31);
      int wv_ = n >> 5, s_ = (n >> 4) & 1, ml_ = n & 15;
      int j_ = k >> 5, q_ = (k >> 3) & 3, e_ = k & 7;
      int dst = ((((wv_ << 1) + s_) * 4 + j_) * 64 + (q_ << 4) + ml_) * 8 + e_;
      w0t[dst] = f2bf(ldf(W0, k * 1024 + col));
    }
    for (int i = tid; i < 128 * 256; i += 256) {
      int k = i >> 7, n = i & 127;
      int col = ((n >> 5) << 8) + (sl << 5) + (n & 31);
      int wv_ = n >> 5, s_ = (n >> 4) & 1, ml_ = n & 15;
      int j_ = k >> 5, q_ = (k >> 3) & 3, e_ = k & 7;
      int dst = ((((wv_ << 1) + s_) * 8 + j_) * 64 + (q_ << 4) + ml_) * 8 + e_;
      r0t[dst] = f2bf(ldf(R0, k * 1024 + col));
    }
    if (tid < 128) {
      int col = ((tid >> 5) << 8) + (sl << 5) + (tid & 31);
      ldsB[tid] = ldf(b0, col);
    }

    float cst[3] = {0.f, 0.f, 0.f};
    const int tokBase = (g * MB + um) * T_STEPS;
    int prMin = 0;                    // cached min L1 progress (ring guard)

    float4 xfA, xfB; uint4 xbf;
    {
      int tok = tokens[tokBase];
      if (isF32) {
        const float* row = (const float*)emb + (u64)tok * E_SZ + (un << 3);
        xfA = *(const float4*)row; xfB = *(const float4*)(row + 4);
      } else {
        xbf = *(const uint4*)((const u16*)emb + (u64)tok * E_SZ + (un << 3));
      }
    }
    __syncthreads();

    const int row0 = (wv << 5) + ml;
    const u16* brA0 = w0t + (u32)(((wv << 1) + 0) * 256 + lfr) * 8;  // +kc*512
    const u16* brB0 = w0t + (u32)(((wv << 1) + 1) * 256 + lfr) * 8;
    const u16* brA2 = r0t + (u32)(((wv << 1) + 0) * 512 + lfr) * 8;  // +j*512
    const u16* brB2 = r0t + (u32)(((wv << 1) + 1) * 512 + lfr) * 8;

    for (int t = 0; t < T_STEPS; t++) {
      // ring guard at top: off the post critical path
      if (t >= RD && prMin < t - RD + 1)
        prMin = wavePollMin(flp, t - RD + 1, lane, dead);

      // commit x_t
      {
        uint4 pk;
        if (isF32) {
          pk.x = (u32)f2bf(xfA.x) | ((u32)f2bf(xfA.y) << 16);
          pk.y = (u32)f2bf(xfA.z) | ((u32)f2bf(xfA.w) << 16);
          pk.z = (u32)f2bf(xfB.x) | ((u32)f2bf(xfB.y) << 16);
          pk.w = (u32)f2bf(xfB.z) | ((u32)f2bf(xfB.w) << 16);
        } else pk = xbf;
        *(uint4*)(ldsX + um * EPAD + (un << 3)) = pk;
      }
      __syncthreads();   // B1: x visible

      float ba = ldsB[row0], bb = ldsB[row0 + 16];
      f32x4 acA = {ba, ba, ba, ba}, acB = {bb, bb, bb, bb};

      // x_t @ W0 (no dependence on h0)
      {
        const u16* ar = ldsX + ml * EPAD + (quad << 3);
#pragma unroll
        for (int kc = 0; kc < 4; kc++) {
          bf16x8 av = *(const bf16x8*)(ar + kc * 32);
          acA = __builtin_amdgcn_mfma_f32_16x16x32_bf16(av, *(const bf16x8*)(brA0 + (kc << 9)), acA, 0, 0, 0);
          acB = __builtin_amdgcn_mfma_f32_16x16x32_bf16(av, *(const bf16x8*)(brB0 + (kc << 9)), acB, 0, 0, 0);
        }
      }

      // h0_{t-1}: wave-split staged gather (own slice short-circuited)
      if (t > 0) {
        const u64* base = g_exH0 +
            (u64)((((t - 1) & (RD - 1)) * NG + g) * NSL) * BSTRIDE;
        stageOne(base, (tagB + t) & 0xFFFFu, stg, wv, ml, quad, skipMy, dead);
      }
      __syncthreads();   // B2: stg visible to all waves

      if (t > 0) {
#pragma unroll
        for (int j = 0; j < NSL; j++) {
          bf16x8 fv = *(const bf16x8*)(stg + (((j << 6) + lfr) << 3));
          acA = __builtin_amdgcn_mfma_f32_16x16x32_bf16(fv, *(const bf16x8*)(brA2 + (j << 9)), acA, 0, 0, 0);
          acB = __builtin_amdgcn_mfma_f32_16x16x32_bf16(fv, *(const bf16x8*)(brB2 + (j << 9)), acB, 0, 0, 0);
        }
      }

      // gates
#pragma unroll
      for (int r = 0; r < 4; r++) {
        int m = (quad << 2) + r;
        float gA = (wv == 2) ? tnh_(acA[r]) : sig_(acA[r]);
        float gB = (wv == 2) ? tnh_(acB[r]) : sig_(acB[r]);
        ldsG[row0 * 17 + m] = gA;
        ldsG[(row0 + 16) * 17 + m] = gB;
      }
      __syncthreads();   // B3

      // cell update -> post + own-slice direct staging for next gather
      if (uS < 12) {
        u64 val = ((u64)((tagB + t + 1) & 0xFFFFu)) << 48;
        u16 hw0 = 0, hw1 = 0, hw2 = 0;
#pragma unroll
        for (int i2 = 0; i2 < 3; i2++) {
          if (i2 < 2 || nFull) {
            int k = kb + i2;
            float iv = ldsG[k * 17 + mB];
            float fv = ldsG[(32 + k) * 17 + mB];
            float gv = ldsG[(64 + k) * 17 + mB];
            float ov = ldsG[(96 + k) * 17 + mB];
            float c = fv * cst[i2] + iv * gv; cst[i2] = c;
            u16 hh = f2bf(ov * tnh_(c));
            if (i2 == 0) hw0 = hh; else if (i2 == 1) hw1 = hh; else hw2 = hh;
            val |= ((u64)hh) << (16 * i2);
          }
        }
        // own-slice fragment write (read by all waves after B2(t+1))
        u16* own = stg + (((sl << 6) + (qS << 4) + mB) << 3) + 3 * sS;
        own[0] = hw0; own[1] = hw1;
        if (nFull) own[2] = hw2;
        u64 elem = (u64)(((t & (RD - 1)) * NG + g) * NSL + sl) * BSTRIDE +
                   mB * 12 + uS;
        __hip_atomic_store(g_exH0 + elem, val,
                           __ATOMIC_RELAXED, __HIP_MEMORY_SCOPE_AGENT);
      }

      // x_{t+1} prefetch in flight across next rendezvous
      if (t + 1 < T_STEPS) {
        int tok = tokens[tokBase + t + 1];
        if (isF32) {
          const float* row = (const float*)emb + (u64)tok * E_SZ + (un << 3);
          xfA = *(const float4*)row; xfB = *(const float4*)(row + 4);
        } else {
          xbf = *(const uint4*)((const u16*)emb + (u64)tok * E_SZ + (un << 3));
        }
      }
    }
  } else {
    // ================= LAYER-1 WORKGROUP =================
    u16* w1t = (u16*)(smem + L1_W1T);
    u16* r1t = (u16*)(smem + L1_R1T);
    u16* stg0 = (u16*)(smem + L1_SG0);
    u16* stg1 = (u16*)(smem + L1_SG1);
    float* ldsG = (float*)(smem + L1_G);
    float* ldsB = (float*)(smem + L1_B);

    for (int i = tid; i < 128 * 256; i += 256) {
      int k = i >> 7, n = i & 127;
      int col = ((n >> 5) << 8) + (sl << 5) + (n & 31);
      int wv_ = n >> 5, s_ = (n >> 4) & 1, ml_ = n & 15;
      int j_ = k >> 5, q_ = (k >> 3) & 3, e_ = k & 7;
      int dst = ((((wv_ << 1) + s_) * 8 + j_) * 64 + (q_ << 4) + ml_) * 8 + e_;
      w1t[dst] = f2bf(ldf(W1, k * 1024 + col));
      r1t[dst] = f2bf(ldf(R1, k * 1024 + col));
    }
    if (tid < 128) {
      int col = ((tid >> 5) << 8) + (sl << 5) + (tid & 31);
      ldsB[tid] = ldf(b1, col);
    }
    __syncthreads();

    float cst[3] = {0.f, 0.f, 0.f};
    const int row0 = (wv << 5) + ml;
    const u16* brA1 = w1t + (u32)(((wv << 1) + 0) * 512 + lfr) * 8;
    const u16* brB1 = w1t + (u32)(((wv << 1) + 1) * 512 + lfr) * 8;
    const u16* brA2 = r1t + (u32)(((wv << 1) + 0) * 512 + lfr) * 8;
    const u16* brB2 = r1t + (u32)(((wv << 1) + 1) * 512 + lfr) * 8;

    for (int t = 0; t < T_STEPS; t++) {
      const u32 e1 = (tagB + t) & 0xFFFFu;        // h1_{t-1} tag
      const u32 e0 = (tagB + t + 1) & 0xFFFFu;    // h0_t tag

      // PHASE A: h0_t (ring-ahead, ready) — full 8-slice gather
      {
        const u64* h0b = g_exH0 +
            (u64)(((t & (RD - 1)) * NG + g) * NSL) * BSTRIDE;
        stageOne(h0b, e0, stg0, wv, ml, quad, -1, dead);
      }
      __syncthreads();   // B1: stg0 visible

      // ring-slot release (all waves' h0 staging done)
      if (tid == 0) {
        __atomic_signal_fence(__ATOMIC_RELEASE);
        __hip_atomic_store(g_pr + ((g << 3) + sl) * 16, t + 1,
                           __ATOMIC_RELAXED, __HIP_MEMORY_SCOPE_AGENT);
      }

      float ba = ldsB[row0], bb = ldsB[row0 + 16];
      f32x4 acA = {ba, ba, ba, ba}, acB = {bb, bb, bb, bb};

      // h0_t @ W1 — executed INSIDE the h1 wait window
#pragma unroll
      for (int j = 0; j < NSL; j++) {
        bf16x8 fv = *(const bf16x8*)(stg0 + (((j << 6) + lfr) << 3));
        acA = __builtin_amdgcn_mfma_f32_16x16x32_bf16(fv, *(const bf16x8*)(brA1 + (j << 9)), acA, 0, 0, 0);
        acB = __builtin_amdgcn_mfma_f32_16x16x32_bf16(fv, *(const bf16x8*)(brB1 + (j << 9)), acB, 0, 0, 0);
      }

      // PHASE B: h1_{t-1} pacing gather (own slice short-circuited)
      if (t > 0) {
        const u64* h1b = g_exH1 +
            (u64)((((t - 1) & 1) * NG + g) * NSL) * BSTRIDE;
        stageOne(h1b, e1, stg1, wv, ml, quad, skipMy, dead);
      }
      __syncthreads();   // B2: stg1 visible

      if (t > 0) {
#pragma unroll
        for (int j = 0; j < NSL; j++) {
          bf16x8 fv = *(const bf16x8*)(stg1 + (((j << 6) + lfr) << 3));
          acA = __builtin_amdgcn_mfma_f32_16x16x32_bf16(fv, *(const bf16x8*)(brA2 + (j << 9)), acA, 0, 0, 0);
          acB = __builtin_amdgcn_mfma_f32_16x16x32_bf16(fv, *(const bf16x8*)(brB2 + (j << 9)), acB, 0, 0, 0);
        }
      }

      // gates
#pragma unroll
      for (int r = 0; r < 4; r++) {
        int m = (quad << 2) + r;
        float gA = (wv == 2) ? tnh_(acA[r]) : sig_(acA[r]);
        float gB = (wv == 2) ? tnh_(acB[r]) : sig_(acB[r]);
        ldsG[row0 * 17 + m] = gA;
        ldsG[(row0 + 16) * 17 + m] = gB;
      }
      __syncthreads();   // B3

      // cell update -> post + own-slice direct staging (for next h1 gather)
      if (uS < 12) {
        u64 val = ((u64)((tagB + t + 1) & 0xFFFFu)) << 48;
        u16 hw0 = 0, hw1 = 0, hw2 = 0;
#pragma unroll
        for (int i2 = 0; i2 < 3; i2++) {
          if (i2 < 2 || nFull) {
            int k = kb + i2;
            float iv = ldsG[k * 17 + mB];
            float fv = ldsG[(32 + k) * 17 + mB];
            float gv = ldsG[(64 + k) * 17 + mB];
            float ov = ldsG[(96 + k) * 17 + mB];
            float c = fv * cst[i2] + iv * gv; cst[i2] = c;
            u16 hh = f2bf(ov * tnh_(c));
            if (i2 == 0) hw0 = hh; else if (i2 == 1) hw1 = hh; else hw2 = hh;
            val |= ((u64)hh) << (16 * i2);
          }
        }
        u16* own = stg1 + (((sl << 6) + (qS << 4) + mB) << 3) + 3 * sS;
        own[0] = hw0; own[1] = hw1;
        if (nFull) own[2] = hw2;
        u64 elem = (u64)(((t & 1) * NG + g) * NSL + sl) * BSTRIDE +
                   mB * 12 + uS;
        __hip_atomic_store(g_exH1 + elem, val,
                           __ATOMIC_RELAXED, __HIP_MEMORY_SCOPE_AGENT);
      }
    }

    // epilogue: logits from h1_{T-1} (staging buffers reused as gather area)
    if (sl == 0) {
      __syncthreads();
      u16* ldsEpi = stg0;   // 8448B needed <= 16384B of SG0+SG1
      const u32 etag = (tagB + T_STEPS) & 0xFFFFu;
      if (uS < 12) {
        for (int sp = 0; sp < 8; sp++) {
          const u64* p = g_exH1 +
              (u64)(((1) * NG + g) * NSL + sp) * BSTRIDE + mB * 12 + uS;
          u64 v; int it = 0;
          while (true) {
            v = ldAtom(p);
            if ((u32)(v >> 48) == etag) break;
            if (dead) break;
            if (++it > POLL_BAIL) { dead = 1; break; }
            if (it > 8) __builtin_amdgcn_s_sleep(1);
          }
          u16* dst = ldsEpi + mB * HS + (sp << 5) + kb;
          dst[0] = (u16)v;
          dst[1] = (u16)(v >> 16);
          if (nFull) dst[2] = (u16)(v >> 32);
        }
      }
      __syncthreads();
      float* woutf = ldsG;
      float* red = ldsG + 272;
      woutf[tid] = ldf(Wout, tid);
      __syncthreads();
      float p = 0.f;
#pragma unroll
      for (int j = 0; j < 16; j++)
        p += bf2f(ldsEpi[um * HS + (un << 4) + j]) * woutf[(un << 4) + j];
      red[um * 17 + un] = p;
      __syncthreads();
      if (tid < 16) {
        float sum = ldf(bout, 0);
#pragma unroll
        for (int j = 0; j < 16; j++) sum += red[tid * 17 + j];
        float val = sig_(sum);
        if (isF32) ((float*)outv)[g * MB + tid] = val;
        else       ((u16*)outv)[g * MB + tid] = f2bf(val);
      }
    }
  }
}

extern "C" void kernel_launch(void* const* d_in, const int* in_sizes, int n_in,
                              void* d_out, int out_size, void* d_ws, size_t ws_size,
                              hipStream_t stream) {
  const int* tokens = (const int*)d_in[0];
  const void* emb  = d_in[1];
  const void* W0   = d_in[2];
  const void* R0   = d_in[3];
  const void* b0   = d_in[4];
  const void* W1   = d_in[5];
  const void* R1   = d_in[6];
  const void* b1   = d_in[7];
  const void* Wout = d_in[8];
  const void* bout = d_in[9];

  hipFuncSetAttribute((const void*)lstm_fused,
                      hipFuncAttributeMaxDynamicSharedMemorySize, SMEM_TOTAL);

  dtype_probe<<<dim3(1), dim3(256), 0, stream>>>(W0);

  // 256 wgs (16 groups x (8 L0 + 8 L1)), 1 wg/CU: co-resident.
  lstm_fused<<<dim3(256), dim3(256), SMEM_TOTAL, stream>>>(
      tokens, emb, W0, R0, b0, W1, R1, b1, Wout, bout, d_out);
}